// Round 4
// baseline (1513.742 us; speedup 1.0000x reference)
//
#include <hip/hip_runtime.h>
#include <math.h>

#define B_   8
#define N_   6
#define D_   41
#define C_   64
#define FH_  16
#define FW_  44
#define HW_  (FH_*FW_)          // 704
#define CHW_ ((D_+C_)*FH_*FW_)  // 73920
#define NPIX (B_*N_*FH_*FW_)    // 33792 (< 65536: pix fits 16 bits)
#define NPT  (NPIX*D_)          // 1385472
#define NXV  200
#define NYV  200
#define YQ   50                 // y-quarter per segment
#define NSEG (B_*NXV*4)         // 6400 segments (b, x, yq)
#define NSEGP 7168              // 7*1024, padded for int4 scan
#define NSCANB 7

// exact-rounding helpers: prevent FMA contraction / reassociation
__device__ __forceinline__ float mul_(float a, float b){ return __fmul_rn(a,b); }
__device__ __forceinline__ float add_(float a, float b){ return __fadd_rn(a,b); }
__device__ __forceinline__ float sub_(float a, float b){ return __fsub_rn(a,b); }

// 3x3 inverse mirroring LAPACK getrf (partial pivot) + getrs (divisions kept)
__device__ void inv3(const float* A, float* X){
  float U[3][3];
  float L[3][3] = {{1.f,0.f,0.f},{0.f,1.f,0.f},{0.f,0.f,1.f}};
  int p[3] = {0,1,2};
  #pragma unroll
  for (int i=0;i<3;i++)
    #pragma unroll
    for (int j=0;j<3;j++) U[i][j] = A[i*3+j];
  #pragma unroll
  for (int k=0;k<3;k++){
    int pr = k; float mx = fabsf(U[k][k]);
    #pragma unroll
    for (int r=0;r<3;r++){
      if (r > k){ float v = fabsf(U[r][k]); if (v > mx){ mx = v; pr = r; } }
    }
    if (pr != k){
      #pragma unroll
      for (int j=0;j<3;j++){ float t=U[k][j]; U[k][j]=U[pr][j]; U[pr][j]=t; }
      #pragma unroll
      for (int j=0;j<3;j++){ if (j<k){ float t=L[k][j]; L[k][j]=L[pr][j]; L[pr][j]=t; } }
      int t=p[k]; p[k]=p[pr]; p[pr]=t;
    }
    #pragma unroll
    for (int r=0;r<3;r++){
      if (r > k){
        float m = __fdiv_rn(U[r][k], U[k][k]);
        L[r][k] = m;
        #pragma unroll
        for (int j=0;j<3;j++){ if (j>k) U[r][j] = sub_(U[r][j], mul_(m, U[k][j])); }
      }
    }
  }
  #pragma unroll
  for (int col=0; col<3; col++){
    float y[3];
    #pragma unroll
    for (int i=0;i<3;i++) y[i] = (p[i]==col) ? 1.f : 0.f;
    #pragma unroll
    for (int i=1;i<3;i++)
      #pragma unroll
      for (int j=0;j<3;j++){ if (j<i) y[i] = sub_(y[i], mul_(L[i][j], y[j])); }
    float x[3];
    #pragma unroll
    for (int i=2;i>=0;i--){
      float t = y[i];
      #pragma unroll
      for (int j=0;j<3;j++){ if (j>i) t = sub_(t, mul_(U[i][j], x[j])); }
      x[i] = __fdiv_rn(t, U[i][i]);
    }
    X[0*3+col]=x[0]; X[1*3+col]=x[1]; X[2*3+col]=x[2];
  }
}

// per-(b,n) params: invPost(9), M = rots@inv(intrins) (9), post_trans(3), trans(3)
__global__ void lss_prep(const float* __restrict__ rots, const float* __restrict__ trans,
                         const float* __restrict__ intrins, const float* __restrict__ post_rots,
                         const float* __restrict__ post_trans, float* __restrict__ cam){
  int t = threadIdx.x;
  if (t >= B_*N_) return;
  float invK[9], invP[9];
  inv3(intrins + t*9, invK);
  inv3(post_rots + t*9, invP);
  const float* R = rots + t*9;
  float M[9];
  #pragma unroll
  for (int i=0;i<3;i++)
    #pragma unroll
    for (int j=0;j<3;j++){
      float s = mul_(R[i*3+0], invK[0*3+j]);
      s = add_(s, mul_(R[i*3+1], invK[1*3+j]));
      s = add_(s, mul_(R[i*3+2], invK[2*3+j]));
      M[i*3+j] = s;
    }
  float* o = cam + t*24;
  #pragma unroll
  for (int i=0;i<9;i++) o[i] = invP[i];
  #pragma unroll
  for (int i=0;i<9;i++) o[9+i] = M[i];
  o[18]=post_trans[t*3+0]; o[19]=post_trans[t*3+1]; o[20]=post_trans[t*3+2];
  o[21]=trans[t*3+0];      o[22]=trans[t*3+1];      o[23]=trans[t*3+2];
}

// exact same rounding chain as the R1 (passing) kernel; returns seg<<6|ylocal or -1
__device__ __forceinline__ int point_seg(const float* __restrict__ cam, int pix, int d){
  int w = pix % FW_; int t = pix / FW_;
  int h = t % FH_;   int bn = t / FH_;
  const float* cp = cam + bn*24;
  float u = mul_((float)w, 703.0f/43.0f);
  float v = mul_((float)h, 17.0f);
  float p0 = sub_(u, cp[18]);
  float p1 = sub_(v, cp[19]);
  float a0 = add_(mul_(cp[0],p0), mul_(cp[1],p1));
  float a1 = add_(mul_(cp[3],p0), mul_(cp[4],p1));
  float a2 = add_(mul_(cp[6],p0), mul_(cp[7],p1));
  float dd = add_(4.0f, (float)d);
  float p2 = sub_(dd, cp[20]);
  float r0 = add_(a0, mul_(cp[2],p2));
  float r1 = add_(a1, mul_(cp[5],p2));
  float r2 = add_(a2, mul_(cp[8],p2));
  float q0 = mul_(r0, r2), q1 = mul_(r1, r2), q2 = r2;
  float g0 = add_(add_(add_(mul_(cp[9], q0), mul_(cp[10],q1)), mul_(cp[11],q2)), cp[21]);
  float g1 = add_(add_(add_(mul_(cp[12],q0), mul_(cp[13],q1)), mul_(cp[14],q2)), cp[22]);
  float g2 = add_(add_(add_(mul_(cp[15],q0), mul_(cp[16],q1)), mul_(cp[17],q2)), cp[23]);
  float bxq = mul_(sub_(g0, -50.0f), 2.0f);
  float byq = mul_(sub_(g1, -50.0f), 2.0f);
  float bzq = __fdiv_rn(sub_(g2, -10.0f), 20.0f);
  int gx=(int)bxq, gy=(int)byq, gz=(int)bzq;
  if ((gx>=0)&(gx<NXV)&(gy>=0)&(gy<NYV)&(gz==0)){
    int b = bn / N_;
    int gyq = gy / YQ;
    int yl  = gy - gyq*YQ;
    int seg = ((b*NXV + gx)<<2) + gyq;
    return (seg<<6) | yl;
  }
  return -1;
}

// per-pixel wave: softmax -> dprobA; channel transpose -> featT; geometry -> segA (+count)
__global__ __launch_bounds__(256) void lss_featprep(const float* __restrict__ feat,
    const float* __restrict__ cam, float* __restrict__ featT, float* __restrict__ dprobA,
    unsigned* __restrict__ segA, int* __restrict__ cnt){
  int wave = threadIdx.x >> 6, lane = threadIdx.x & 63;
  int pix = blockIdx.x*4 + wave;
  if (pix >= NPIX) return;
  int w = pix % FW_; int t = pix / FW_;
  int h = t % FH_;   int bn = t / FH_;
  const float* fb = feat + (size_t)bn*CHW_ + h*FW_ + w;
  float logit = (lane < D_) ? fb[(size_t)lane*HW_] : -INFINITY;
  float mx = logit;
  #pragma unroll
  for (int o=32;o;o>>=1) mx = fmaxf(mx, __shfl_xor(mx,o));
  float e = (lane < D_) ? expf(logit - mx) : 0.f;
  float ssum = e;
  #pragma unroll
  for (int o=32;o;o>>=1) ssum += __shfl_xor(ssum,o);
  featT[(size_t)pix*C_ + lane] = fb[(size_t)(D_+lane)*HW_];
  if (lane < D_){
    dprobA[pix*D_ + lane] = e / ssum;
    int sv = point_seg(cam, pix, lane);
    unsigned pk = 0xFFFFFFFFu;
    if (sv >= 0){ pk = (unsigned)sv; atomicAdd(&cnt[sv>>6], 1); }
    segA[pix*D_ + lane] = pk;
  }
}

// ---- 3-kernel exclusive scan over NSEGP (padded with zeros) ----
__global__ __launch_bounds__(256) void scan_sums(const int* __restrict__ cnt,
                                                 int* __restrict__ bsum){
  int b = blockIdx.x, t = threadIdx.x;
  int4 v = ((const int4*)(cnt + b*1024))[t];
  int s = v.x+v.y+v.z+v.w;
  #pragma unroll
  for (int o=32;o;o>>=1) s += __shfl_xor(s,o);
  __shared__ int ws[4];
  if ((t&63)==0) ws[t>>6] = s;
  __syncthreads();
  if (t==0) bsum[b] = ws[0]+ws[1]+ws[2]+ws[3];
}

__global__ __launch_bounds__(512) void scan_mid(const int* __restrict__ bsum,
                                                int* __restrict__ ebsum){
  __shared__ int s[512];
  int t = threadIdx.x;
  int v = (t < NSCANB) ? bsum[t] : 0;
  s[t] = v; __syncthreads();
  for (int o=1;o<512;o<<=1){
    int u = (t>=o) ? s[t-o] : 0;
    __syncthreads();
    s[t] += u;
    __syncthreads();
  }
  if (t < NSCANB) ebsum[t] = s[t] - v;
}

__global__ __launch_bounds__(256) void scan_final(const int* __restrict__ cnt,
    const int* __restrict__ ebsum, int* __restrict__ offs){
  int b = blockIdx.x, t = threadIdx.x, lane = t&63, w = t>>6;
  int4 v = ((const int4*)(cnt + b*1024))[t];
  int s = v.x+v.y+v.z+v.w;
  int incl = s;
  #pragma unroll
  for (int o=1;o<64;o<<=1){ int u = __shfl_up(incl,o); if (lane>=o) incl += u; }
  __shared__ int ws[4];
  if (lane==63) ws[w] = incl;
  __syncthreads();
  int base = ebsum[b];
  #pragma unroll
  for (int i=0;i<3;i++){ if (i < w) base += ws[i]; }
  int excl = base + incl - s;
  int4 o4; o4.x = excl; o4.y = excl+v.x; o4.z = o4.y+v.y; o4.w = o4.z+v.z;
  ((int4*)(offs + b*1024))[t] = o4;
}

// pure shuffle: no geometry recompute (segA/dprobA were cached by featprep)
__global__ __launch_bounds__(256) void lss_fill(const unsigned* __restrict__ segA,
    const float* __restrict__ dprobA, int* __restrict__ cur, uint2* __restrict__ rec){
  int tid = blockIdx.x*256 + threadIdx.x;
  if (tid >= NPT) return;
  unsigned pk = segA[tid];
  if (pk != 0xFFFFFFFFu){
    int s  = pk >> 6;
    int yl = pk & 63;
    int pix = tid / D_;
    int pos = atomicAdd(&cur[s], 1);
    uint2 r; r.x = (unsigned)pix | ((unsigned)yl << 16); r.y = __float_as_uint(dprobA[tid]);
    rec[pos] = r;
  }
}

// one block per segment: 4 waves consume point list in parallel (lane = channel),
// accumulate via LDS f32 atomics, write out[b][c][x][yq*50..] exactly once.
__global__ __launch_bounds__(256) void lss_accum(const float* __restrict__ featT,
    const uint2* __restrict__ rec, const int* __restrict__ offs, float* __restrict__ out){
  __shared__ float lds[YQ][C_+1];
  int s  = blockIdx.x;
  int yq = s & 3;
  int x  = (s >> 2) % NXV;
  int b  = s / (NXV*4);
  int tid = threadIdx.x, lane = tid & 63, wv = tid >> 6;
  for (int i = tid; i < YQ*(C_+1); i += 256) ((float*)lds)[i] = 0.f;
  __syncthreads();
  int st = offs[s], en = offs[s+1];
  int c  = en - st;
  int chunk = (c + 3) >> 2;
  int j0 = st + wv*chunk;
  int j1 = j0 + chunk; if (j1 > en) j1 = en;
  if (j0 < j1){
    uint2 r = rec[j0];
    float f = featT[(size_t)(r.x & 0xFFFFu)*C_ + lane];
    for (int j = j0; j < j1; j++){
      uint2 rn = r; float fn = f;
      if (j+1 < j1){
        rn = rec[j+1];
        fn = featT[(size_t)(rn.x & 0xFFFFu)*C_ + lane];
      }
      int yl = (r.x >> 16) & 63;
      atomicAdd(&lds[yl][lane], __uint_as_float(r.y) * f);
      r = rn; f = fn;
    }
  }
  __syncthreads();
  for (int i = tid; i < C_*YQ; i += 256){
    int cc = i / YQ, y = i - cc*YQ;
    out[(((size_t)(b*C_ + cc))*NXV + x)*NYV + yq*YQ + y] = lds[y][cc];
  }
}

// R1 fallback: direct atomics into out (only used if ws is unexpectedly small)
__global__ __launch_bounds__(256) void lss_scatter_fb(const float* __restrict__ feat,
    const float* __restrict__ cam, float* __restrict__ pooled){
  int wave = threadIdx.x >> 6, lane = threadIdx.x & 63;
  int pix = blockIdx.x*4 + wave;
  if (pix >= NPIX) return;
  int w = pix % FW_; int t = pix / FW_;
  int h = t % FH_;   t /= FH_;
  int n = t % N_;    int b = t / N_;
  const float* fb = feat + (size_t)(b*N_+n)*CHW_ + h*FW_ + w;
  float logit = (lane < D_) ? fb[(size_t)lane*HW_] : -INFINITY;
  float mx = logit;
  #pragma unroll
  for (int o=32;o;o>>=1) mx = fmaxf(mx, __shfl_xor(mx,o));
  float e = (lane < D_) ? expf(logit - mx) : 0.f;
  float ssum = e;
  #pragma unroll
  for (int o=32;o;o>>=1) ssum += __shfl_xor(ssum,o);
  float dprob = e / ssum;
  float fc = fb[(size_t)(D_+lane)*HW_];
  for (int d=0; d<D_; d++){
    int pk = point_seg(cam, pix, d);
    if (pk >= 0){
      int seg = pk >> 6;
      int gx = (seg >> 2) % NXV;
      int gy = (seg & 3)*YQ + (pk & 63);
      float dp = __shfl(dprob, d);
      atomicAdd(&pooled[(((size_t)b*C_ + lane)*NXV + gx)*NYV + gy], mul_(dp, fc));
    }
  }
}

extern "C" void kernel_launch(void* const* d_in, const int* in_sizes, int n_in,
                              void* d_out, int out_size, void* d_ws, size_t ws_size,
                              hipStream_t stream) {
  const float* feat       = (const float*)d_in[0];
  const float* rots       = (const float*)d_in[1];
  const float* trans      = (const float*)d_in[2];
  const float* intrins    = (const float*)d_in[3];
  const float* post_rots  = (const float*)d_in[4];
  const float* post_trans = (const float*)d_in[5];
  float* out = (float*)d_out;

  // ws layout (256B-aligned chunks)
  char* p = (char*)d_ws;
  float*    cam    = (float*)p;    p += 48*24*4 + 256;
  float*    featT  = (float*)p;    p += (size_t)NPIX*C_*4;   // 8.65 MB
  float*    dprobA = (float*)p;    p += (size_t)NPT*4;       // 5.54 MB
  unsigned* segA   = (unsigned*)p; p += (size_t)NPT*4;       // 5.54 MB
  int*      cnt    = (int*)p;      p += (size_t)NSEGP*4;     // 28.7 KB
  int*      offs   = (int*)p;      p += (size_t)NSEGP*4;
  int*      cur    = (int*)p;      p += (size_t)NSEGP*4;
  int*      bsum   = (int*)p;      p += 1024;
  int*      ebsum  = (int*)p;      p += 1024;
  uint2*    rec    = (uint2*)p;    p += (size_t)NPT*8;       // 11.1 MB
  size_t need = (size_t)(p - (char*)d_ws);

  if (ws_size < need){
    hipMemsetAsync(d_out, 0, (size_t)out_size*sizeof(float), stream);
    lss_prep<<<1, 64, 0, stream>>>(rots, trans, intrins, post_rots, post_trans, (float*)d_ws);
    lss_scatter_fb<<<NPIX/4, 256, 0, stream>>>(feat, (float*)d_ws, out);
    return;
  }

  hipMemsetAsync(cnt, 0, (size_t)NSEGP*4, stream);
  lss_prep<<<1, 64, 0, stream>>>(rots, trans, intrins, post_rots, post_trans, cam);
  lss_featprep<<<NPIX/4, 256, 0, stream>>>(feat, cam, featT, dprobA, segA, cnt);
  scan_sums<<<NSCANB, 256, 0, stream>>>(cnt, bsum);
  scan_mid<<<1, 512, 0, stream>>>(bsum, ebsum);
  scan_final<<<NSCANB, 256, 0, stream>>>(cnt, ebsum, offs);
  hipMemcpyAsync(cur, offs, (size_t)NSEGP*4, hipMemcpyDeviceToDevice, stream);
  lss_fill<<<NPT/256, 256, 0, stream>>>(segA, dprobA, cur, rec);
  lss_accum<<<NSEG, 256, 0, stream>>>(featT, rec, offs, out);
}

// Round 5
// 101.105 us; speedup vs baseline: 14.9720x; 14.9720x over previous
//
#include <hip/hip_runtime.h>
#include <math.h>

#define B_   8
#define N_   6
#define D_   41
#define C_   64
#define FH_  16
#define FW_  44
#define HW_  (FH_*FW_)          // 704
#define CHW_ ((D_+C_)*FH_*FW_)  // 73920
#define NPIX (B_*N_*FH_*FW_)    // 33792
#define NPT  (NPIX*D_)          // 1385472
#define NXV  200
#define NYV  200
#define NVOX (B_*NXV*NYV)       // 320000
#define NCOL (B_*N_*FW_)        // 2112 columns (b,n,w)
#define DCH  7
#define NCHUNK 6                // ceil(41/7)

// exact-rounding helpers: prevent FMA contraction / reassociation
__device__ __forceinline__ float mul_(float a, float b){ return __fmul_rn(a,b); }
__device__ __forceinline__ float add_(float a, float b){ return __fadd_rn(a,b); }
__device__ __forceinline__ float sub_(float a, float b){ return __fsub_rn(a,b); }

// 3x3 inverse mirroring LAPACK getrf (partial pivot) + getrs (divisions kept)
__device__ void inv3(const float* A, float* X){
  float U[3][3];
  float L[3][3] = {{1.f,0.f,0.f},{0.f,1.f,0.f},{0.f,0.f,1.f}};
  int p[3] = {0,1,2};
  #pragma unroll
  for (int i=0;i<3;i++)
    #pragma unroll
    for (int j=0;j<3;j++) U[i][j] = A[i*3+j];
  #pragma unroll
  for (int k=0;k<3;k++){
    int pr = k; float mx = fabsf(U[k][k]);
    #pragma unroll
    for (int r=0;r<3;r++){
      if (r > k){ float v = fabsf(U[r][k]); if (v > mx){ mx = v; pr = r; } }
    }
    if (pr != k){
      #pragma unroll
      for (int j=0;j<3;j++){ float t=U[k][j]; U[k][j]=U[pr][j]; U[pr][j]=t; }
      #pragma unroll
      for (int j=0;j<3;j++){ if (j<k){ float t=L[k][j]; L[k][j]=L[pr][j]; L[pr][j]=t; } }
      int t=p[k]; p[k]=p[pr]; p[pr]=t;
    }
    #pragma unroll
    for (int r=0;r<3;r++){
      if (r > k){
        float m = __fdiv_rn(U[r][k], U[k][k]);
        L[r][k] = m;
        #pragma unroll
        for (int j=0;j<3;j++){ if (j>k) U[r][j] = sub_(U[r][j], mul_(m, U[k][j])); }
      }
    }
  }
  #pragma unroll
  for (int col=0; col<3; col++){
    float y[3];
    #pragma unroll
    for (int i=0;i<3;i++) y[i] = (p[i]==col) ? 1.f : 0.f;
    #pragma unroll
    for (int i=1;i<3;i++)
      #pragma unroll
      for (int j=0;j<3;j++){ if (j<i) y[i] = sub_(y[i], mul_(L[i][j], y[j])); }
    float x[3];
    #pragma unroll
    for (int i=2;i>=0;i--){
      float t = y[i];
      #pragma unroll
      for (int j=0;j<3;j++){ if (j>i) t = sub_(t, mul_(U[i][j], x[j])); }
      x[i] = __fdiv_rn(t, U[i][i]);
    }
    X[0*3+col]=x[0]; X[1*3+col]=x[1]; X[2*3+col]=x[2];
  }
}

// per-(b,n) params: invPost(9), M = rots@inv(intrins) (9), post_trans(3), trans(3)
__global__ void lss_prep(const float* __restrict__ rots, const float* __restrict__ trans,
                         const float* __restrict__ intrins, const float* __restrict__ post_rots,
                         const float* __restrict__ post_trans, float* __restrict__ cam){
  int t = threadIdx.x;
  if (t >= B_*N_) return;
  float invK[9], invP[9];
  inv3(intrins + t*9, invK);
  inv3(post_rots + t*9, invP);
  const float* R = rots + t*9;
  float M[9];
  #pragma unroll
  for (int i=0;i<3;i++)
    #pragma unroll
    for (int j=0;j<3;j++){
      float s = mul_(R[i*3+0], invK[0*3+j]);
      s = add_(s, mul_(R[i*3+1], invK[1*3+j]));
      s = add_(s, mul_(R[i*3+2], invK[2*3+j]));
      M[i*3+j] = s;
    }
  float* o = cam + t*24;
  #pragma unroll
  for (int i=0;i<9;i++) o[i] = invP[i];
  #pragma unroll
  for (int i=0;i<9;i++) o[9+i] = M[i];
  o[18]=post_trans[t*3+0]; o[19]=post_trans[t*3+1]; o[20]=post_trans[t*3+2];
  o[21]=trans[t*3+0];      o[22]=trans[t*3+1];      o[23]=trans[t*3+2];
}

// exact same rounding chain as the R1 (passing) kernel; returns voxel id or -1
__device__ __forceinline__ int point_vox(const float* __restrict__ cam,
                                         int bn, int h, int w, int d){
  const float* cp = cam + bn*24;
  float u = mul_((float)w, 703.0f/43.0f);
  float v = mul_((float)h, 17.0f);
  float p0 = sub_(u, cp[18]);
  float p1 = sub_(v, cp[19]);
  float a0 = add_(mul_(cp[0],p0), mul_(cp[1],p1));
  float a1 = add_(mul_(cp[3],p0), mul_(cp[4],p1));
  float a2 = add_(mul_(cp[6],p0), mul_(cp[7],p1));
  float dd = add_(4.0f, (float)d);
  float p2 = sub_(dd, cp[20]);
  float r0 = add_(a0, mul_(cp[2],p2));
  float r1 = add_(a1, mul_(cp[5],p2));
  float r2 = add_(a2, mul_(cp[8],p2));
  float q0 = mul_(r0, r2), q1 = mul_(r1, r2), q2 = r2;
  float g0 = add_(add_(add_(mul_(cp[9], q0), mul_(cp[10],q1)), mul_(cp[11],q2)), cp[21]);
  float g1 = add_(add_(add_(mul_(cp[12],q0), mul_(cp[13],q1)), mul_(cp[14],q2)), cp[22]);
  float g2 = add_(add_(add_(mul_(cp[15],q0), mul_(cp[16],q1)), mul_(cp[17],q2)), cp[23]);
  float bxq = mul_(sub_(g0, -50.0f), 2.0f);
  float byq = mul_(sub_(g1, -50.0f), 2.0f);
  float bzq = __fdiv_rn(sub_(g2, -10.0f), 20.0f);
  int gx=(int)bxq, gy=(int)byq, gz=(int)bzq;
  int b = bn / N_;
  if ((gx>=0)&(gx<NXV)&(gy>=0)&(gy<NYV)&(gz==0))
    return (b*NXV + gx)*NYV + gy;
  return -1;
}

// block per (bn,h): LDS-staged coalesced transpose + softmax + cached geometry.
// NO atomics anywhere in this kernel.
__global__ __launch_bounds__(256) void lss_featprep(const float* __restrict__ feat,
    const float* __restrict__ cam, float* __restrict__ featT, float* __restrict__ dprobA,
    unsigned* __restrict__ segA){
  __shared__ float lds[D_+C_][FW_+1];   // 105 x 45
  __shared__ float ssum[FW_];
  int bid = blockIdx.x;                 // bn*16 + h
  int h = bid & 15, bn = bid >> 4;
  int tid = threadIdx.x;
  const float* fb = feat + (size_t)bn*CHW_ + h*FW_;
  for (int i = tid; i < (D_+C_)*FW_; i += 256){
    int ch = i / FW_, w = i - ch*FW_;
    lds[ch][w] = fb[(size_t)ch*HW_ + w];
  }
  __syncthreads();
  if (tid < FW_){
    float m = lds[0][tid];
    for (int d = 1; d < D_; d++) m = fmaxf(m, lds[d][tid]);
    float s = 0.f;
    for (int d = 0; d < D_; d++){ float e = expf(lds[d][tid] - m); lds[d][tid] = e; s += e; }
    ssum[tid] = s;
  }
  __syncthreads();
  int pix0 = bid * FW_;
  // featT[pix][c], coalesced over c
  for (int i = tid; i < C_*FW_; i += 256){
    int w = i >> 6, c = i & 63;
    featT[(size_t)(pix0 + w)*C_ + c] = lds[D_ + c][w];
  }
  // per-point dprob + voxel id, coalesced over d
  for (int i = tid; i < D_*FW_; i += 256){
    int w = i / D_, d = i - w*D_;
    int pix = pix0 + w;
    dprobA[(size_t)pix*D_ + d] = __fdiv_rn(lds[d][w], ssum[w]);
    int v = point_vox(cam, bn, h, w, d);
    segA[(size_t)pix*D_ + d] = (v < 0) ? 0xFFFFFFFFu : (unsigned)v;
  }
}

// one wave per (column, d-chunk); lane = channel. 16 h-rows of a (b,n,w,d) group
// hit the same voxel -> register run accumulation, one 64-lane atomic per run.
__global__ __launch_bounds__(256) void lss_cols(const float* __restrict__ featT,
    const unsigned* __restrict__ segA, const float* __restrict__ dprobA,
    float* __restrict__ pooled, unsigned char* __restrict__ flags){
  int wv = threadIdx.x >> 6, lane = threadIdx.x & 63;
  int gid = blockIdx.x*4 + wv;                 // grid exact: NCOL*NCHUNK/4 blocks
  int col = gid / NCHUNK, chunk = gid - col*NCHUNK;
  int w = col % FW_, bn = col / FW_;
  int pixbase = bn*(FH_*FW_) + w;              // pixel at h=0
  float fT[16];
  #pragma unroll
  for (int h = 0; h < 16; h++)
    fT[h] = featT[(size_t)(pixbase + h*FW_)*C_ + lane];
  int d0 = chunk*DCH;
  int dlen = (d0 + DCH <= D_) ? DCH : (D_ - d0);
  unsigned curv = 0xFFFFFFFFu; float acc = 0.f;
  for (int dd = 0; dd < dlen; dd++){
    int d = d0 + dd;
    unsigned sv = 0xFFFFFFFFu; float dp = 0.f;
    if (lane < 16){
      size_t pt = (size_t)(pixbase + lane*FW_)*D_ + d;
      sv = segA[pt];
      dp = dprobA[pt];
    }
    #pragma unroll
    for (int h = 0; h < 16; h++){
      unsigned v = __shfl(sv, h);
      float p  = __shfl(dp, h);
      if (v == 0xFFFFFFFFu) continue;          // culled point: don't break the run
      if (v != curv){
        if (curv != 0xFFFFFFFFu){
          atomicAdd(&pooled[(size_t)curv*C_ + lane], acc);
          if (lane == 0) flags[curv] = 1;
        }
        curv = v; acc = 0.f;
      }
      acc = fmaf(p, fT[h], acc);
    }
  }
  if (curv != 0xFFFFFFFFu){
    atomicAdd(&pooled[(size_t)curv*C_ + lane], acc);
    if (lane == 0) flags[curv] = 1;
  }
}

// pooled[b][x][y][c] -> out[b][c][x][y]; flag-skip untouched voxels (they are zero)
__global__ __launch_bounds__(256) void lss_transpose(const float* __restrict__ pooled,
    const unsigned char* __restrict__ flags, float* __restrict__ out){
  __shared__ float lds[50][C_+1];
  int bid = blockIdx.x;           // ((b*200)+x)*4 + q
  int q = bid & 3;
  int x = (bid >> 2) % NXV;
  int b = bid / (NXV*4);
  int y0 = q*50;
  int tid = threadIdx.x, lane = tid & 63, wv = tid >> 6;
  int vbase = (b*NXV + x)*NYV + y0;
  for (int yl = wv; yl < 50; yl += 4){
    float val = 0.f;
    if (flags[vbase + yl]) val = pooled[(size_t)(vbase + yl)*C_ + lane];
    lds[yl][lane] = val;
  }
  __syncthreads();
  for (int i = tid; i < C_*50; i += 256){
    int cc = i / 50, y = i - cc*50;
    out[((size_t)(b*C_ + cc)*NXV + x)*NYV + y0 + y] = lds[y][cc];
  }
}

// R1 fallback: direct atomics into out (only used if ws is unexpectedly small)
__global__ __launch_bounds__(256) void lss_scatter_fb(const float* __restrict__ feat,
    const float* __restrict__ cam, float* __restrict__ pooled){
  int wave = threadIdx.x >> 6, lane = threadIdx.x & 63;
  int pix = blockIdx.x*4 + wave;
  if (pix >= NPIX) return;
  int w = pix % FW_; int t = pix / FW_;
  int h = t % FH_;   int bn = t / FH_;
  int b = bn / N_;
  const float* fb = feat + (size_t)bn*CHW_ + h*FW_ + w;
  float logit = (lane < D_) ? fb[(size_t)lane*HW_] : -INFINITY;
  float mx = logit;
  #pragma unroll
  for (int o=32;o;o>>=1) mx = fmaxf(mx, __shfl_xor(mx,o));
  float e = (lane < D_) ? expf(logit - mx) : 0.f;
  float ssum = e;
  #pragma unroll
  for (int o=32;o;o>>=1) ssum += __shfl_xor(ssum,o);
  float dprob = e / ssum;
  float fc = fb[(size_t)(D_+lane)*HW_];
  for (int d=0; d<D_; d++){
    int v = point_vox(cam, bn, h, w, d);
    if (v >= 0){
      int gx = (v / NYV) % NXV, gy = v % NYV;
      float dp = __shfl(dprob, d);
      atomicAdd(&pooled[(((size_t)b*C_ + lane)*NXV + gx)*NYV + gy], mul_(dp, fc));
    }
  }
}

extern "C" void kernel_launch(void* const* d_in, const int* in_sizes, int n_in,
                              void* d_out, int out_size, void* d_ws, size_t ws_size,
                              hipStream_t stream) {
  const float* feat       = (const float*)d_in[0];
  const float* rots       = (const float*)d_in[1];
  const float* trans      = (const float*)d_in[2];
  const float* intrins    = (const float*)d_in[3];
  const float* post_rots  = (const float*)d_in[4];
  const float* post_trans = (const float*)d_in[5];
  float* out = (float*)d_out;

  // ws layout: pooled + flags contiguous (single memset), then caches
  char* p = (char*)d_ws;
  float*         pooled = (float*)p;         p += (size_t)NVOX*C_*4;   // 81.92 MB
  unsigned char* flags  = (unsigned char*)p; p += NVOX;                // 0.32 MB
  float*         cam    = (float*)p;         p += 48*24*4 + 256;
  float*         featT  = (float*)p;         p += (size_t)NPIX*C_*4;   // 8.65 MB
  float*         dprobA = (float*)p;         p += (size_t)NPT*4;       // 5.54 MB
  unsigned*      segA   = (unsigned*)p;      p += (size_t)NPT*4;       // 5.54 MB
  size_t need = (size_t)(p - (char*)d_ws);

  if (ws_size < need){
    // fallback (R1 structure): needs only cam in ws
    hipMemsetAsync(d_out, 0, (size_t)out_size*sizeof(float), stream);
    lss_prep<<<1, 64, 0, stream>>>(rots, trans, intrins, post_rots, post_trans, (float*)d_ws);
    lss_scatter_fb<<<NPIX/4, 256, 0, stream>>>(feat, (float*)d_ws, out);
    return;
  }

  hipMemsetAsync(pooled, 0, (size_t)NVOX*C_*4 + NVOX, stream);  // pooled + flags
  lss_prep<<<1, 64, 0, stream>>>(rots, trans, intrins, post_rots, post_trans, cam);
  lss_featprep<<<B_*N_*FH_, 256, 0, stream>>>(feat, cam, featT, dprobA, segA);
  lss_cols<<<NCOL*NCHUNK/4, 256, 0, stream>>>(featT, segA, dprobA, pooled, flags);
  lss_transpose<<<B_*NXV*4, 256, 0, stream>>>(pooled, flags, out);
}

// Round 6
// 92.297 us; speedup vs baseline: 16.4008x; 1.0954x over previous
//
#include <hip/hip_runtime.h>
#include <math.h>

#define B_   8
#define N_   6
#define D_   41
#define C_   64
#define FH_  16
#define FW_  44
#define HW_  (FH_*FW_)          // 704
#define CHW_ ((D_+C_)*FH_*FW_)  // 73920
#define NPIX (B_*N_*FH_*FW_)    // 33792
#define NPT  (NPIX*D_)          // 1385472
#define NXV  200
#define NYV  200
#define NVOX (B_*NXV*NYV)       // 320000
#define NCOL (B_*N_*FW_)        // 2112 columns (b,n,w)
#define DCH  7
#define NCHUNK 6                // ceil(41/7)
#define FEATBLKS (B_*N_*FH_)    // 768
#define ZEROBLKS 1280
#define NZ4 ((NVOX*C_*4 + NVOX)/16)   // float4 count of pooled+flags = 5,140,000

// exact-rounding helpers: prevent FMA contraction / reassociation
__device__ __forceinline__ float mul_(float a, float b){ return __fmul_rn(a,b); }
__device__ __forceinline__ float add_(float a, float b){ return __fadd_rn(a,b); }
__device__ __forceinline__ float sub_(float a, float b){ return __fsub_rn(a,b); }

// 3x3 inverse mirroring LAPACK getrf (partial pivot) + getrs (divisions kept)
__device__ void inv3(const float* A, float* X){
  float U[3][3];
  float L[3][3] = {{1.f,0.f,0.f},{0.f,1.f,0.f},{0.f,0.f,1.f}};
  int p[3] = {0,1,2};
  #pragma unroll
  for (int i=0;i<3;i++)
    #pragma unroll
    for (int j=0;j<3;j++) U[i][j] = A[i*3+j];
  #pragma unroll
  for (int k=0;k<3;k++){
    int pr = k; float mx = fabsf(U[k][k]);
    #pragma unroll
    for (int r=0;r<3;r++){
      if (r > k){ float v = fabsf(U[r][k]); if (v > mx){ mx = v; pr = r; } }
    }
    if (pr != k){
      #pragma unroll
      for (int j=0;j<3;j++){ float t=U[k][j]; U[k][j]=U[pr][j]; U[pr][j]=t; }
      #pragma unroll
      for (int j=0;j<3;j++){ if (j<k){ float t=L[k][j]; L[k][j]=L[pr][j]; L[pr][j]=t; } }
      int t=p[k]; p[k]=p[pr]; p[pr]=t;
    }
    #pragma unroll
    for (int r=0;r<3;r++){
      if (r > k){
        float m = __fdiv_rn(U[r][k], U[k][k]);
        L[r][k] = m;
        #pragma unroll
        for (int j=0;j<3;j++){ if (j>k) U[r][j] = sub_(U[r][j], mul_(m, U[k][j])); }
      }
    }
  }
  #pragma unroll
  for (int col=0; col<3; col++){
    float y[3];
    #pragma unroll
    for (int i=0;i<3;i++) y[i] = (p[i]==col) ? 1.f : 0.f;
    #pragma unroll
    for (int i=1;i<3;i++)
      #pragma unroll
      for (int j=0;j<3;j++){ if (j<i) y[i] = sub_(y[i], mul_(L[i][j], y[j])); }
    float x[3];
    #pragma unroll
    for (int i=2;i>=0;i--){
      float t = y[i];
      #pragma unroll
      for (int j=0;j<3;j++){ if (j>i) t = sub_(t, mul_(U[i][j], x[j])); }
      x[i] = __fdiv_rn(t, U[i][i]);
    }
    X[0*3+col]=x[0]; X[1*3+col]=x[1]; X[2*3+col]=x[2];
  }
}

// compute the 24 per-(b,n) cam params (identical arithmetic to original lss_prep)
__device__ void cam_params(const float* __restrict__ rots, const float* __restrict__ trans,
                           const float* __restrict__ intrins, const float* __restrict__ post_rots,
                           const float* __restrict__ post_trans, int t, float* o){
  float invK[9], invP[9];
  inv3(intrins + t*9, invK);
  inv3(post_rots + t*9, invP);
  const float* R = rots + t*9;
  #pragma unroll
  for (int i=0;i<9;i++) o[i] = invP[i];
  #pragma unroll
  for (int i=0;i<3;i++)
    #pragma unroll
    for (int j=0;j<3;j++){
      float s = mul_(R[i*3+0], invK[0*3+j]);
      s = add_(s, mul_(R[i*3+1], invK[1*3+j]));
      s = add_(s, mul_(R[i*3+2], invK[2*3+j]));
      o[9 + i*3+j] = s;
    }
  o[18]=post_trans[t*3+0]; o[19]=post_trans[t*3+1]; o[20]=post_trans[t*3+2];
  o[21]=trans[t*3+0];      o[22]=trans[t*3+1];      o[23]=trans[t*3+2];
}

// exact same rounding chain as the R1 (passing) kernel; returns voxel id or -1
__device__ __forceinline__ int point_vox(const float* __restrict__ cp,
                                         int b, int h, int w, int d){
  float u = mul_((float)w, 703.0f/43.0f);
  float v = mul_((float)h, 17.0f);
  float p0 = sub_(u, cp[18]);
  float p1 = sub_(v, cp[19]);
  float a0 = add_(mul_(cp[0],p0), mul_(cp[1],p1));
  float a1 = add_(mul_(cp[3],p0), mul_(cp[4],p1));
  float a2 = add_(mul_(cp[6],p0), mul_(cp[7],p1));
  float dd = add_(4.0f, (float)d);
  float p2 = sub_(dd, cp[20]);
  float r0 = add_(a0, mul_(cp[2],p2));
  float r1 = add_(a1, mul_(cp[5],p2));
  float r2 = add_(a2, mul_(cp[8],p2));
  float q0 = mul_(r0, r2), q1 = mul_(r1, r2), q2 = r2;
  float g0 = add_(add_(add_(mul_(cp[9], q0), mul_(cp[10],q1)), mul_(cp[11],q2)), cp[21]);
  float g1 = add_(add_(add_(mul_(cp[12],q0), mul_(cp[13],q1)), mul_(cp[14],q2)), cp[22]);
  float g2 = add_(add_(add_(mul_(cp[15],q0), mul_(cp[16],q1)), mul_(cp[17],q2)), cp[23]);
  float bxq = mul_(sub_(g0, -50.0f), 2.0f);
  float byq = mul_(sub_(g1, -50.0f), 2.0f);
  float bzq = __fdiv_rn(sub_(g2, -10.0f), 20.0f);
  int gx=(int)bxq, gy=(int)byq, gz=(int)bzq;
  if ((gx>=0)&(gx<NXV)&(gy>=0)&(gy<NYV)&(gz==0))
    return (b*NXV + gx)*NYV + gy;
  return -1;
}

// Fused kernel. Blocks [0,FEATBLKS): per-(bn,h) feature transpose + softmax +
// cached geometry (cam params computed in-block). Blocks [FEATBLKS,+ZEROBLKS):
// float4 zero-fill of pooled+flags (pure BW, overlaps featprep compute).
__global__ __launch_bounds__(256) void lss_featprep(const float* __restrict__ feat,
    const float* __restrict__ rots, const float* __restrict__ trans,
    const float* __restrict__ intrins, const float* __restrict__ post_rots,
    const float* __restrict__ post_trans,
    float* __restrict__ featT, float* __restrict__ dprobA, unsigned* __restrict__ segA,
    float4* __restrict__ zero_dst){
  int bid = blockIdx.x;
  int tid = threadIdx.x;
  if (bid >= FEATBLKS){
    // ---- zero-fill role ----
    const float4 z = make_float4(0.f,0.f,0.f,0.f);
    size_t i = (size_t)(bid - FEATBLKS)*256 + tid;
    #pragma unroll
    for (int k=0; k<16; k++){
      if (i < NZ4) zero_dst[i] = z;
      i += (size_t)ZEROBLKS*256;
    }
    return;
  }
  // ---- featprep role ----
  __shared__ float lds[D_+C_][FW_+1];   // 105 x 45
  __shared__ float ssum[FW_];
  __shared__ float cam[24];
  int h = bid & 15, bn = bid >> 4;
  if (tid == 0)
    cam_params(rots, trans, intrins, post_rots, post_trans, bn, cam);
  const float* fb = feat + (size_t)bn*CHW_ + h*FW_;
  for (int i = tid; i < (D_+C_)*FW_; i += 256){
    int ch = i / FW_, w = i - ch*FW_;
    lds[ch][w] = fb[(size_t)ch*HW_ + w];
  }
  __syncthreads();
  if (tid < FW_){
    float m = lds[0][tid];
    for (int d = 1; d < D_; d++) m = fmaxf(m, lds[d][tid]);
    float s = 0.f;
    for (int d = 0; d < D_; d++){ float e = expf(lds[d][tid] - m); lds[d][tid] = e; s += e; }
    ssum[tid] = s;
  }
  __syncthreads();
  int pix0 = bid * FW_;
  int b = bn / N_;
  // featT[pix][c], coalesced over c
  for (int i = tid; i < C_*FW_; i += 256){
    int w = i >> 6, c = i & 63;
    featT[(size_t)(pix0 + w)*C_ + c] = lds[D_ + c][w];
  }
  // per-point dprob + voxel id, coalesced over d
  for (int i = tid; i < D_*FW_; i += 256){
    int w = i / D_, d = i - w*D_;
    int pix = pix0 + w;
    dprobA[(size_t)pix*D_ + d] = __fdiv_rn(lds[d][w], ssum[w]);
    int v = point_vox(cam, b, h, w, d);
    segA[(size_t)pix*D_ + d] = (v < 0) ? 0xFFFFFFFFu : (unsigned)v;
  }
}

// one wave per (column, d-chunk); lane = channel. 16 h-rows of a (b,n,w,d) group
// hit the same voxel -> register run accumulation, one 64-lane atomic per run.
__global__ __launch_bounds__(256) void lss_cols(const float* __restrict__ featT,
    const unsigned* __restrict__ segA, const float* __restrict__ dprobA,
    float* __restrict__ pooled, unsigned char* __restrict__ flags){
  int wv = threadIdx.x >> 6, lane = threadIdx.x & 63;
  int gid = blockIdx.x*4 + wv;                 // grid exact: NCOL*NCHUNK/4 blocks
  int col = gid / NCHUNK, chunk = gid - col*NCHUNK;
  int w = col % FW_, bn = col / FW_;
  int pixbase = bn*(FH_*FW_) + w;              // pixel at h=0
  float fT[16];
  #pragma unroll
  for (int h = 0; h < 16; h++)
    fT[h] = featT[(size_t)(pixbase + h*FW_)*C_ + lane];
  int d0 = chunk*DCH;
  int dlen = (d0 + DCH <= D_) ? DCH : (D_ - d0);
  unsigned curv = 0xFFFFFFFFu; float acc = 0.f;
  for (int dd = 0; dd < dlen; dd++){
    int d = d0 + dd;
    unsigned sv = 0xFFFFFFFFu; float dp = 0.f;
    if (lane < 16){
      size_t pt = (size_t)(pixbase + lane*FW_)*D_ + d;
      sv = segA[pt];
      dp = dprobA[pt];
    }
    #pragma unroll
    for (int h = 0; h < 16; h++){
      unsigned v = __shfl(sv, h);
      float p  = __shfl(dp, h);
      if (v == 0xFFFFFFFFu) continue;          // culled point: don't break the run
      if (v != curv){
        if (curv != 0xFFFFFFFFu){
          atomicAdd(&pooled[(size_t)curv*C_ + lane], acc);
          if (lane == 0) flags[curv] = 1;
        }
        curv = v; acc = 0.f;
      }
      acc = fmaf(p, fT[h], acc);
    }
  }
  if (curv != 0xFFFFFFFFu){
    atomicAdd(&pooled[(size_t)curv*C_ + lane], acc);
    if (lane == 0) flags[curv] = 1;
  }
}

// pooled[b][x][y][c] -> out[b][c][x][y]; flag-skip untouched voxels (they are zero)
__global__ __launch_bounds__(256) void lss_transpose(const float* __restrict__ pooled,
    const unsigned char* __restrict__ flags, float* __restrict__ out){
  __shared__ float lds[50][C_+1];
  int bid = blockIdx.x;           // ((b*200)+x)*4 + q
  int q = bid & 3;
  int x = (bid >> 2) % NXV;
  int b = bid / (NXV*4);
  int y0 = q*50;
  int tid = threadIdx.x, lane = tid & 63, wv = tid >> 6;
  int vbase = (b*NXV + x)*NYV + y0;
  for (int yl = wv; yl < 50; yl += 4){
    float val = 0.f;
    if (flags[vbase + yl]) val = pooled[(size_t)(vbase + yl)*C_ + lane];
    lds[yl][lane] = val;
  }
  __syncthreads();
  for (int i = tid; i < C_*50; i += 256){
    int cc = i / 50, y = i - cc*50;
    out[((size_t)(b*C_ + cc)*NXV + x)*NYV + y0 + y] = lds[y][cc];
  }
}

// fallback path (ws too small): per-(b,n) cam params to ws, then direct atomics
__global__ void lss_prep(const float* __restrict__ rots, const float* __restrict__ trans,
                         const float* __restrict__ intrins, const float* __restrict__ post_rots,
                         const float* __restrict__ post_trans, float* __restrict__ cam){
  int t = threadIdx.x;
  if (t >= B_*N_) return;
  cam_params(rots, trans, intrins, post_rots, post_trans, t, cam + t*24);
}

__global__ __launch_bounds__(256) void lss_scatter_fb(const float* __restrict__ feat,
    const float* __restrict__ cam, float* __restrict__ pooled){
  int wave = threadIdx.x >> 6, lane = threadIdx.x & 63;
  int pix = blockIdx.x*4 + wave;
  if (pix >= NPIX) return;
  int w = pix % FW_; int t = pix / FW_;
  int h = t % FH_;   int bn = t / FH_;
  int b = bn / N_;
  const float* fb = feat + (size_t)bn*CHW_ + h*FW_ + w;
  float logit = (lane < D_) ? fb[(size_t)lane*HW_] : -INFINITY;
  float mx = logit;
  #pragma unroll
  for (int o=32;o;o>>=1) mx = fmaxf(mx, __shfl_xor(mx,o));
  float e = (lane < D_) ? expf(logit - mx) : 0.f;
  float ssum = e;
  #pragma unroll
  for (int o=32;o;o>>=1) ssum += __shfl_xor(ssum,o);
  float dprob = e / ssum;
  float fc = fb[(size_t)(D_+lane)*HW_];
  for (int d=0; d<D_; d++){
    int v = point_vox(cam + bn*24, b, h, w, d);
    if (v >= 0){
      int gx = (v / NYV) % NXV, gy = v % NYV;
      float dp = __shfl(dprob, d);
      atomicAdd(&pooled[(((size_t)b*C_ + lane)*NXV + gx)*NYV + gy], mul_(dp, fc));
    }
  }
}

extern "C" void kernel_launch(void* const* d_in, const int* in_sizes, int n_in,
                              void* d_out, int out_size, void* d_ws, size_t ws_size,
                              hipStream_t stream) {
  const float* feat       = (const float*)d_in[0];
  const float* rots       = (const float*)d_in[1];
  const float* trans      = (const float*)d_in[2];
  const float* intrins    = (const float*)d_in[3];
  const float* post_rots  = (const float*)d_in[4];
  const float* post_trans = (const float*)d_in[5];
  float* out = (float*)d_out;

  // ws layout: pooled + flags contiguous (zeroed by fused kernel), then caches
  char* p = (char*)d_ws;
  float*         pooled = (float*)p;         p += (size_t)NVOX*C_*4;   // 81.92 MB
  unsigned char* flags  = (unsigned char*)p; p += NVOX;                // 0.32 MB
  float*         featT  = (float*)p;         p += (size_t)NPIX*C_*4;   // 8.65 MB
  float*         dprobA = (float*)p;         p += (size_t)NPT*4;       // 5.54 MB
  unsigned*      segA   = (unsigned*)p;      p += (size_t)NPT*4;       // 5.54 MB
  size_t need = (size_t)(p - (char*)d_ws);

  if (ws_size < need){
    // fallback (R1 structure): needs only cam in ws
    hipMemsetAsync(d_out, 0, (size_t)out_size*sizeof(float), stream);
    lss_prep<<<1, 64, 0, stream>>>(rots, trans, intrins, post_rots, post_trans, (float*)d_ws);
    lss_scatter_fb<<<NPIX/4, 256, 0, stream>>>(feat, (float*)d_ws, out);
    return;
  }

  lss_featprep<<<FEATBLKS + ZEROBLKS, 256, 0, stream>>>(
      feat, rots, trans, intrins, post_rots, post_trans,
      featT, dprobA, segA, (float4*)pooled);
  lss_cols<<<NCOL*NCHUNK/4, 256, 0, stream>>>(featT, segA, dprobA, pooled, flags);
  lss_transpose<<<B_*NXV*4, 256, 0, stream>>>(pooled, flags, out);
}